// Round 3
// baseline (2324.332 us; speedup 1.0000x reference)
//
#include <hip/hip_runtime.h>

// ModalVerlet: B=16, M=64, T=48000. One lane per (b,m); serial scan in registers.
//
// Scaled-state recurrence: carry z = C*q with C = 2*log2(e), folding tanh's
// input scaling into the constants. tanh(q) = 1 - 2*r, r = rcp(exp2(z)+1).
// Loop-carried critical chain per step (4 dependent ops):
//     z = fma(CAGBm2g2, r_prev, VC)  ->  exp2(z)  ->  +1  ->  rcp
// Everything else (t, cb, VC, q, c, gc, p) hangs off the chain with >=1-step
// slack. 13 VALU ops/step total.
//
// Round-2 lessons baked in: NO nontemporal scalar stores (partial-line HBM
// writes tripled WRITE_SIZE), outputs finalized in-step and buffered into
// float4 groups -> 8 aligned dwordx4 cached stores per 16-step iteration, so
// L2 merges each lane's 64B line and store-data registers live a full
// iteration (no vmcnt recycle stalls).

#define NB 16
#define NM 64
#define NT 48000
#define SPI 16
#define NITER (NT / SPI) // 3000

__global__ void __launch_bounds__(NM, 1) modal_scan_kernel(
    const float* __restrict__ y0,
    const float* __restrict__ omega,
    const float* __restrict__ sigma,
    const float* __restrict__ gamma,
    const float* __restrict__ Phi_e,
    const float* __restrict__ fe_points,
    float* __restrict__ y_out)
{
    const int b = blockIdx.x;
    const int m = threadIdx.x;

    const float om  = omega[b * NM + m];
    const float sg  = sigma[b * NM + m];
    const float g   = gamma[b];
    const float phe = Phi_e[b * NM + m];
    const float om2 = om * om;
    const float g2  = g * g;

    const float k    = 1.0f / 48000.0f;
    const float k2   = 0.5f * k;
    const float E    = 1.0f - k * sg;
    const float dinv = 1.0f / (1.0f + k * sg);
    const float A    = k * E;          // q_s = q_{s-1} + A*p_{s-1} + Bc*c_{s-1}
    const float Bc   = k * k2;
    const float Fd   = E * dinv;       // p_s = Fd*p_{s-1} + Gd*c_{s-1} + Gd*c_s
    const float Gd   = k2 * dinv;
    const float AGB  = A * Gd + Bc;
    const float m2g2 = -2.0f * g2;

    const float C    = 2.885390081777927f;   // 2*log2(e)
    const float invC = 0.34657359027997264f; // ln(2)/2
    const float CA   = C * A;
    const float CAGB = C * AGB;
    const float CAGBm2g2 = CAGB * m2g2;
    const float mom2C = -om2 * invC;

    const float q0v = y0[b * 2 * NM + m];
    const float p0v = y0[b * 2 * NM + NM + m];

    const float*  fe  = fe_points + (size_t)b * NT;
    const float4* fe4 = reinterpret_cast<const float4*>(fe);
    float* yq = y_out + ((size_t)b * 2 * NM + m) * (size_t)NT;
    float* yp = yq + (size_t)NM * NT;

    // ---- preamble: state 0 ----
    float4 fc0 = fe4[0], fc1 = fe4[1], fc2 = fe4[2], fc3 = fe4[3];

    float z0  = C * q0v;
    float r0  = __builtin_amdgcn_rcpf(__builtin_amdgcn_exp2f(z0) + 1.0f);
    float cb0 = fmaf(mom2C, z0, fmaf(phe, fc0.x, g2));
    float c0  = fmaf(m2g2, r0, cb0);
    float gcP = Gd * c0;
    float t0  = fmaf(-Gd, c0, p0v);         // t_0 such that p_0 = t_0 + Gd*c_0
    float VC  = fmaf(CAGB, cb0, fmaf(CA, t0, z0)); // VC_1
    float rP  = r0;
    float pP  = p0v;

    // Step producing state s. QO/PO are output-buffer lvalues for q_s, p_s.
#define STEP(FE, QO, PO) {                                           \
    float z  = fmaf(CAGBm2g2, rP, VC);           /* [CHAIN] z_s   */ \
    float t  = fmaf(Fd, pP, gcP);                /* t_s           */ \
    float e  = __builtin_amdgcn_exp2f(z);        /* [CHAIN]       */ \
    float cb = fmaf(mom2C, z, fmaf(phe, (FE), g2));                  \
    VC = fmaf(CAGB, cb, fmaf(CA, t, z));         /* VC_{s+1}      */ \
    QO = invC * z;                                                   \
    float r  = __builtin_amdgcn_rcpf(e + 1.0f);  /* [CHAIN]       */ \
    float c  = fmaf(m2g2, r, cb);                                    \
    gcP = Gd * c;                                                    \
    PO  = t + gcP;                               /* p_s           */ \
    rP = r; pP = PO; }

    // ---- iteration 0: states 0..15 ----
    {
        float4 oq0, oq1, oq2, oq3, op0, op1, op2, op3;
        oq0.x = q0v; op0.x = p0v;
        STEP(fc0.y, oq0.y, op0.y);
        STEP(fc0.z, oq0.z, op0.z);
        STEP(fc0.w, oq0.w, op0.w);
        STEP(fc1.x, oq1.x, op1.x);
        STEP(fc1.y, oq1.y, op1.y);
        STEP(fc1.z, oq1.z, op1.z);
        STEP(fc1.w, oq1.w, op1.w);
        STEP(fc2.x, oq2.x, op2.x);
        STEP(fc2.y, oq2.y, op2.y);
        STEP(fc2.z, oq2.z, op2.z);
        STEP(fc2.w, oq2.w, op2.w);
        STEP(fc3.x, oq3.x, op3.x);
        STEP(fc3.y, oq3.y, op3.y);
        STEP(fc3.z, oq3.z, op3.z);
        STEP(fc3.w, oq3.w, op3.w);
        reinterpret_cast<float4*>(yq)[0] = oq0;
        reinterpret_cast<float4*>(yq)[1] = oq1;
        reinterpret_cast<float4*>(yq)[2] = oq2;
        reinterpret_cast<float4*>(yq)[3] = oq3;
        reinterpret_cast<float4*>(yp)[0] = op0;
        reinterpret_cast<float4*>(yp)[1] = op1;
        reinterpret_cast<float4*>(yp)[2] = op2;
        reinterpret_cast<float4*>(yp)[3] = op3;
    }

    // ---- main loop: iter j covers states 16j..16j+15 ----
    float4 fn0 = fe4[4], fn1 = fe4[5], fn2 = fe4[6], fn3 = fe4[7];
    for (int j = 1; j < NITER; ++j) {
        fc0 = fn0; fc1 = fn1; fc2 = fn2; fc3 = fn3;
        const int jn = (j + 1 < NITER) ? (j + 1) : (NITER - 1);
        fn0 = fe4[4 * jn + 0]; fn1 = fe4[4 * jn + 1];
        fn2 = fe4[4 * jn + 2]; fn3 = fe4[4 * jn + 3];

        float4 oq0, oq1, oq2, oq3, op0, op1, op2, op3;
        STEP(fc0.x, oq0.x, op0.x);
        STEP(fc0.y, oq0.y, op0.y);
        STEP(fc0.z, oq0.z, op0.z);
        STEP(fc0.w, oq0.w, op0.w);
        STEP(fc1.x, oq1.x, op1.x);
        STEP(fc1.y, oq1.y, op1.y);
        STEP(fc1.z, oq1.z, op1.z);
        STEP(fc1.w, oq1.w, op1.w);
        STEP(fc2.x, oq2.x, op2.x);
        STEP(fc2.y, oq2.y, op2.y);
        STEP(fc2.z, oq2.z, op2.z);
        STEP(fc2.w, oq2.w, op2.w);
        STEP(fc3.x, oq3.x, op3.x);
        STEP(fc3.y, oq3.y, op3.y);
        STEP(fc3.z, oq3.z, op3.z);
        STEP(fc3.w, oq3.w, op3.w);

        float4* yq4 = reinterpret_cast<float4*>(yq + 16 * (size_t)j);
        float4* yp4 = reinterpret_cast<float4*>(yp + 16 * (size_t)j);
        yq4[0] = oq0; yq4[1] = oq1; yq4[2] = oq2; yq4[3] = oq3;
        yp4[0] = op0; yp4[1] = op1; yp4[2] = op2; yp4[3] = op3;
    }
#undef STEP
}

// w[b,t] = sum_m Phi_o[b,m] * y[b,m,t]  (fully parallel, memory/L3-bound)
__global__ void __launch_bounds__(256) w_kernel(
    const float* __restrict__ y,
    const float* __restrict__ Phi_o,
    float* __restrict__ w)
{
    const int b  = blockIdx.y;
    const int t4 = blockIdx.x * 256 + threadIdx.x;
    if (t4 >= NT / 4) return;

    const float4* yb = reinterpret_cast<const float4*>(y + (size_t)b * 2 * NM * NT);
    const float*  po = Phi_o + b * NM;

    float4 acc = make_float4(0.f, 0.f, 0.f, 0.f);
    #pragma unroll 8
    for (int mm = 0; mm < NM; ++mm) {
        float  c = po[mm];
        float4 v = yb[mm * (NT / 4) + t4];
        acc.x = fmaf(c, v.x, acc.x);
        acc.y = fmaf(c, v.y, acc.y);
        acc.z = fmaf(c, v.z, acc.z);
        acc.w = fmaf(c, v.w, acc.w);
    }
    reinterpret_cast<float4*>(w + (size_t)b * NT)[t4] = acc;
}

extern "C" void kernel_launch(void* const* d_in, const int* in_sizes, int n_in,
                              void* d_out, int out_size, void* d_ws, size_t ws_size,
                              hipStream_t stream)
{
    // inputs: 0=fs, 1=num_samples, 2=y0, 3=omega, 4=sigma, 5=gamma,
    //         6=Phi_e, 7=Phi_o, 8=fe_points
    const float* y0    = (const float*)d_in[2];
    const float* omega = (const float*)d_in[3];
    const float* sigma = (const float*)d_in[4];
    const float* gamma = (const float*)d_in[5];
    const float* Phi_e = (const float*)d_in[6];
    const float* Phi_o = (const float*)d_in[7];
    const float* fe    = (const float*)d_in[8];

    float* y_out = (float*)d_out;                    // (B, 2M, T)
    float* w_out = y_out + (size_t)NB * 2 * NM * NT; // (B, T)

    modal_scan_kernel<<<NB, NM, 0, stream>>>(y0, omega, sigma, gamma, Phi_e, fe, y_out);

    dim3 grid((NT / 4 + 255) / 256, NB);
    w_kernel<<<grid, 256, 0, stream>>>(y_out, Phi_o, w_out);
}

// Round 4
// 1737.269 us; speedup vs baseline: 1.3379x; 1.3379x over previous
//
#include <hip/hip_runtime.h>

// ModalVerlet: B=16, M=64, T=48000. Producer/consumer wave specialization.
//
// Wave 0 (scan): one lane per mode, serial 48000-step recurrence in registers.
//   Scaled-state form: z = C*q, C = 2*log2(e); tanh(q) = 1 - 2*r,
//   r = rcp(exp2(z)+1). Loop-carried chain per step (4 dependent ops):
//       z = fma(CAGBm2g2, r_prev, VC) -> exp2 -> +1 -> rcp
//   Outputs go ONLY to LDS (ds_write_b32, t-major [SPI][64], conflict-free).
//   This wave issues no global stores -> no vmcnt store-ack stalls (rounds 2/3
//   lost ~1300 cyc/iter to store-data register reuse waits; the allocator
//   refuses to buffer outputs in registers).
//
// Wave 1 (storer): after each barrier, reads the previous LDS slot (column
//   reads, bank-conflict-free) and issues the global_store_dwordx4s. Its
//   vmcnt waits sit in ~1000 cyc of slack per iteration.
//
// Double-buffered LDS slots, one s_barrier per SPI=32 steps, equal barrier
// counts on both waves (standard producer/consumer; wave-uniform branches).

#define NB 16
#define NM 64
#define NT 48000
#define SPI 32
#define NITER (NT / SPI) // 1500

__global__ void __launch_bounds__(128, 1) modal_scan_kernel(
    const float* __restrict__ y0,
    const float* __restrict__ omega,
    const float* __restrict__ sigma,
    const float* __restrict__ gamma,
    const float* __restrict__ Phi_e,
    const float* __restrict__ fe_points,
    float* __restrict__ y_out)
{
    const int b   = blockIdx.x;
    const int wid = threadIdx.x >> 6;
    const int m   = threadIdx.x & 63;

    __shared__ float lq[2][SPI][NM];
    __shared__ float lp[2][SPI][NM];

    if (wid == 0) {
        // ---------------- scan wave ----------------
        const float om  = omega[b * NM + m];
        const float sg  = sigma[b * NM + m];
        const float g   = gamma[b];
        const float phe = Phi_e[b * NM + m];
        const float om2 = om * om;
        const float g2  = g * g;

        const float k    = 1.0f / 48000.0f;
        const float k2   = 0.5f * k;
        const float E    = 1.0f - k * sg;
        const float dinv = 1.0f / (1.0f + k * sg);
        const float A    = k * E;          // q_s = q_{s-1} + A*p_{s-1} + Bc*c_{s-1}
        const float Bc   = k * k2;
        const float Fd   = E * dinv;       // p_s = Fd*p_{s-1} + Gd*(c_{s-1}+c_s)
        const float Gd   = k2 * dinv;
        const float AGB  = A * Gd + Bc;
        const float m2g2 = -2.0f * g2;

        const float C    = 2.885390081777927f;   // 2*log2(e)
        const float invC = 0.34657359027997264f; // ln(2)/2
        const float CA   = C * A;
        const float CAGB = C * AGB;
        const float CAGBm2g2 = CAGB * m2g2;
        const float mom2C = -om2 * invC;

        const float q0v = y0[b * 2 * NM + m];
        const float p0v = y0[b * 2 * NM + NM + m];

        const float4* fe4 = reinterpret_cast<const float4*>(fe_points + (size_t)b * NT);

        float4 fc[8], fn[8];
#pragma unroll
        for (int i = 0; i < 8; ++i) fc[i] = fe4[i];

        // preamble: state 0
        float z0  = C * q0v;
        float r0  = __builtin_amdgcn_rcpf(__builtin_amdgcn_exp2f(z0) + 1.0f);
        float cb0 = fmaf(mom2C, z0, fmaf(phe, fc[0].x, g2));
        float c0  = fmaf(m2g2, r0, cb0);
        float gcP = Gd * c0;
        float t0  = fmaf(-Gd, c0, p0v);               // p_0 = t_0 + Gd*c_0
        float VC  = fmaf(CAGB, cb0, fmaf(CA, t0, z0)); // VC_1
        float rP  = r0;
        float pP  = p0v;

#define STEP(FE, SL, T) {                                  \
    float z  = fmaf(CAGBm2g2, rP, VC);   /* [CHAIN] */     \
    float t_ = fmaf(Fd, pP, gcP);                          \
    float e  = __builtin_amdgcn_exp2f(z); /* [CHAIN] */    \
    float cb = fmaf(mom2C, z, fmaf(phe, (FE), g2));        \
    VC = fmaf(CAGB, cb, fmaf(CA, t_, z));                  \
    lq[SL][T][m] = invC * z;                               \
    float r  = __builtin_amdgcn_rcpf(e + 1.0f); /*CHAIN*/  \
    float c  = fmaf(m2g2, r, cb);                          \
    gcP = Gd * c;                                          \
    float p  = t_ + gcP;                                   \
    lp[SL][T][m] = p;                                      \
    rP = r; pP = p; }

#define STEP4(SL, F, T) \
    STEP((F).x, SL, (T) + 0); STEP((F).y, SL, (T) + 1); \
    STEP((F).z, SL, (T) + 2); STEP((F).w, SL, (T) + 3);

        // ---- iteration 0: states 0..31 into slot 0 ----
        lq[0][0][m] = q0v;
        lp[0][0][m] = p0v;
        STEP(fc[0].y, 0, 1);
        STEP(fc[0].z, 0, 2);
        STEP(fc[0].w, 0, 3);
        STEP4(0, fc[1], 4);
        STEP4(0, fc[2], 8);
        STEP4(0, fc[3], 12);
        STEP4(0, fc[4], 16);
        STEP4(0, fc[5], 20);
        STEP4(0, fc[6], 24);
        STEP4(0, fc[7], 28);
        __syncthreads();

        // ---- main loop: iter j covers states 32j..32j+31 ----
        for (int j = 1; j < NITER; ++j) {
            const int jn = (j + 1 < NITER) ? (j + 1) : (NITER - 1);
#pragma unroll
            for (int i = 0; i < 8; ++i) fn[i] = fe4[8 * jn + i];

            const int sl = j & 1;
            STEP4(sl, fc[0], 0);
            STEP4(sl, fc[1], 4);
            STEP4(sl, fc[2], 8);
            STEP4(sl, fc[3], 12);
            STEP4(sl, fc[4], 16);
            STEP4(sl, fc[5], 20);
            STEP4(sl, fc[6], 24);
            STEP4(sl, fc[7], 28);
            __syncthreads();
#pragma unroll
            for (int i = 0; i < 8; ++i) fc[i] = fn[i];
        }
#undef STEP4
#undef STEP
    } else {
        // ---------------- storer wave ----------------
        float* yql = y_out + ((size_t)b * 2 * NM + m) * (size_t)NT;
        float* ypl = yql + (size_t)NM * NT;

        for (int j = 0; j < NITER; ++j) {
            __syncthreads();
            const int sl = j & 1;

            float q[SPI], p[SPI];
#pragma unroll
            for (int t = 0; t < SPI; ++t) {
                q[t] = lq[sl][t][m];
                p[t] = lp[sl][t][m];
            }

            float4* dq = reinterpret_cast<float4*>(yql + (size_t)SPI * j);
            float4* dp = reinterpret_cast<float4*>(ypl + (size_t)SPI * j);
#pragma unroll
            for (int i = 0; i < SPI / 4; ++i) {
                dq[i] = make_float4(q[4 * i], q[4 * i + 1], q[4 * i + 2], q[4 * i + 3]);
                dp[i] = make_float4(p[4 * i], p[4 * i + 1], p[4 * i + 2], p[4 * i + 3]);
            }
        }
    }
}

// w[b,t] = sum_m Phi_o[b,m] * y[b,m,t]  (fully parallel, memory/L3-bound)
__global__ void __launch_bounds__(256) w_kernel(
    const float* __restrict__ y,
    const float* __restrict__ Phi_o,
    float* __restrict__ w)
{
    const int b  = blockIdx.y;
    const int t4 = blockIdx.x * 256 + threadIdx.x;
    if (t4 >= NT / 4) return;

    const float4* yb = reinterpret_cast<const float4*>(y + (size_t)b * 2 * NM * NT);
    const float*  po = Phi_o + b * NM;

    float4 acc = make_float4(0.f, 0.f, 0.f, 0.f);
    #pragma unroll 8
    for (int mm = 0; mm < NM; ++mm) {
        float  c = po[mm];
        float4 v = yb[mm * (NT / 4) + t4];
        acc.x = fmaf(c, v.x, acc.x);
        acc.y = fmaf(c, v.y, acc.y);
        acc.z = fmaf(c, v.z, acc.z);
        acc.w = fmaf(c, v.w, acc.w);
    }
    reinterpret_cast<float4*>(w + (size_t)b * NT)[t4] = acc;
}

extern "C" void kernel_launch(void* const* d_in, const int* in_sizes, int n_in,
                              void* d_out, int out_size, void* d_ws, size_t ws_size,
                              hipStream_t stream)
{
    // inputs: 0=fs, 1=num_samples, 2=y0, 3=omega, 4=sigma, 5=gamma,
    //         6=Phi_e, 7=Phi_o, 8=fe_points
    const float* y0    = (const float*)d_in[2];
    const float* omega = (const float*)d_in[3];
    const float* sigma = (const float*)d_in[4];
    const float* gamma = (const float*)d_in[5];
    const float* Phi_e = (const float*)d_in[6];
    const float* Phi_o = (const float*)d_in[7];
    const float* fe    = (const float*)d_in[8];

    float* y_out = (float*)d_out;                    // (B, 2M, T)
    float* w_out = y_out + (size_t)NB * 2 * NM * NT; // (B, T)

    modal_scan_kernel<<<NB, 128, 0, stream>>>(y0, omega, sigma, gamma, Phi_e, fe, y_out);

    dim3 grid((NT / 4 + 255) / 256, NB);
    w_kernel<<<grid, 256, 0, stream>>>(y_out, Phi_o, w_out);
}

// Round 5
// 1519.548 us; speedup vs baseline: 1.5296x; 1.1433x over previous
//
#include <hip/hip_runtime.h>

// ModalVerlet: B=16, M=64, T=48000. Producer/consumer wave specialization.
//
// Wave 0 (scan): one lane per mode, serial 48000-step recurrence in registers.
// Chain restructure (round 5): the direct r->z coupling has coefficient
// CAGB*m2g2 ~ 1e-8, so the z-update uses r lagged ONE step (error <=1e-10/step,
// below fp32 rounding); the physically-strong tanh path flows through the
// t-recurrence t' = Fd*t + GdF1*c (exact algebra), where c uses the EXACT r_s
// that was issued (exp2/rcp) during the previous step's block -> ~1 step of
// slack, transcendental latency fully hidden.
//   Loop-carried chain per step: cz = fma(mom2C,z,hs) -> kl = fma(m2g2,rB,cz)
//   -> zn = fma(CAGB,kl,W)   == 3 fmas ~ 12 cyc  (was fma->exp2->add->rcp ~56).
// Per step: 10 VALU + 2 trans + 1 ds_write_b64 (z,p packed; q=invC*z done by
// the storer wave, which has slack).
//
// Wave 1 (storer): after each barrier reads the previous LDS slot (float2
// (z,p) per (t,m), conflict-free), computes q = invC*z, packs float4, issues
// global_store_dwordx4. Its vmcnt waits sit in its per-iteration slack.

#define NB 16
#define NM 64
#define NT 48000
#define SPI 32
#define NITER (NT / SPI) // 1500

__global__ void __launch_bounds__(128, 1) modal_scan_kernel(
    const float* __restrict__ y0,
    const float* __restrict__ omega,
    const float* __restrict__ sigma,
    const float* __restrict__ gamma,
    const float* __restrict__ Phi_e,
    const float* __restrict__ fe_points,
    float* __restrict__ y_out)
{
    const int b   = blockIdx.x;
    const int wid = threadIdx.x >> 6;
    const int m   = threadIdx.x & 63;

    __shared__ float2 lzp[2][SPI][NM];

    if (wid == 0) {
        // ---------------- scan wave ----------------
        const float om  = omega[b * NM + m];
        const float sg  = sigma[b * NM + m];
        const float g   = gamma[b];
        const float phe = Phi_e[b * NM + m];
        const float om2 = om * om;
        const float g2  = g * g;

        const float k    = 1.0f / 48000.0f;
        const float k2   = 0.5f * k;
        const float E    = 1.0f - k * sg;
        const float dinv = 1.0f / (1.0f + k * sg);
        const float A    = k * E;          // q_s+1 = q_s + A*t_s + AGB*c_s
        const float Bc   = k * k2;
        const float Fd   = E * dinv;       // p_s = t_s + Gd*c_s
        const float Gd   = k2 * dinv;      // t_s+1 = Fd*t_s + GdF1*c_s
        const float AGB  = A * Gd + Bc;
        const float m2g2 = -2.0f * g2;

        const float C    = 2.885390081777927f;   // 2*log2(e)
        const float CA   = C * A;
        const float CAGB = C * AGB;
        const float invC = 0.34657359027997264f; // ln(2)/2
        const float mom2C = -om2 * invC;
        const float GdF1 = Gd * (1.0f + Fd);

        const float q0v = y0[b * 2 * NM + m];
        const float p0v = y0[b * 2 * NM + NM + m];

        const float4* fe4 = reinterpret_cast<const float4*>(fe_points + (size_t)b * NT);

        float4 bufA[8], bufB[8];
#pragma unroll
        for (int i = 0; i < 8; ++i) bufA[i] = fe4[i];
#pragma unroll
        for (int i = 0; i < 8; ++i) bufB[i] = fe4[8 + i];

        // ---- preamble: state 0 ----
        float z  = C * q0v;
        float rA = __builtin_amdgcn_rcpf(__builtin_amdgcn_exp2f(z) + 1.0f); // r_0
        float rB = rA;  // "r_{-1}" := r_0 (exact at step 0)
        float hs0 = fmaf(phe, bufA[0].x, g2);
        float c0  = fmaf(m2g2, rA, fmaf(mom2C, z, hs0));
        float t   = fmaf(-Gd, c0, p0v);   // p_0 = t_0 + Gd*c_0

        // Step producing/writing state s, advancing to s+1.
        // rB = r_{s-1} (z-path, lagged), rA = r_s (exact, p/t-path).
#define STEP(FE, SL, T) {                                   \
    float hs = fmaf(phe, (FE), g2);                         \
    float cz = fmaf(mom2C, z, hs);       /* [CHAIN] */      \
    float kl = fmaf(m2g2, rB, cz);       /* [CHAIN] */      \
    float W  = fmaf(CA, t, z);                              \
    float zn = fmaf(CAGB, kl, W);        /* [CHAIN] z_s+1 */\
    float kp = fmaf(m2g2, rA, cz);       /* c_s (exact r) */\
    float p  = fmaf(Gd, kp, t);          /* p_s           */\
    lzp[SL][T][m] = make_float2(z, p);                      \
    t = fmaf(Fd, t, GdF1 * kp);          /* t_s+1         */\
    float en = __builtin_amdgcn_exp2f(zn);                  \
    float rn = __builtin_amdgcn_rcpf(en + 1.0f); /* r_s+1 */\
    rB = rA; rA = rn; z = zn; }

#define STEP4(SL, F, T) \
    STEP((F).x, SL, (T)+0); STEP((F).y, SL, (T)+1); \
    STEP((F).z, SL, (T)+2); STEP((F).w, SL, (T)+3);

#define STEP32(SL, BUF) \
    STEP4(SL, BUF[0], 0);  STEP4(SL, BUF[1], 4); \
    STEP4(SL, BUF[2], 8);  STEP4(SL, BUF[3], 12); \
    STEP4(SL, BUF[4], 16); STEP4(SL, BUF[5], 20); \
    STEP4(SL, BUF[6], 24); STEP4(SL, BUF[7], 28);

        // j-loop unrolled by 2: even iters consume bufA (slot 0), odd bufB
        // (slot 1); each buffer refilled right after consumption (~1.5 iters
        // of prefetch distance, no register copies).
        for (int j = 0; j < NITER; j += 2) {
            STEP32(0, bufA);
            {
                const int jn = (j + 2 < NITER) ? (j + 2) : j;
#pragma unroll
                for (int i = 0; i < 8; ++i) bufA[i] = fe4[8 * jn + i];
            }
            __syncthreads();

            STEP32(1, bufB);
            {
                const int jn = (j + 3 < NITER) ? (j + 3) : (j + 1);
#pragma unroll
                for (int i = 0; i < 8; ++i) bufB[i] = fe4[8 * jn + i];
            }
            __syncthreads();
        }
#undef STEP32
#undef STEP4
#undef STEP
    } else {
        // ---------------- storer wave ----------------
        float* yql = y_out + ((size_t)b * 2 * NM + m) * (size_t)NT;
        float* ypl = yql + (size_t)NM * NT;
        const float invC = 0.34657359027997264f;

        for (int j = 0; j < NITER; ++j) {
            __syncthreads();
            const int sl = j & 1;

            float q[SPI], p[SPI];
#pragma unroll
            for (int t = 0; t < SPI; ++t) {
                float2 v = lzp[sl][t][m];
                q[t] = invC * v.x;
                p[t] = v.y;
            }

            float4* dq = reinterpret_cast<float4*>(yql + (size_t)SPI * j);
            float4* dp = reinterpret_cast<float4*>(ypl + (size_t)SPI * j);
#pragma unroll
            for (int i = 0; i < SPI / 4; ++i) {
                dq[i] = make_float4(q[4 * i], q[4 * i + 1], q[4 * i + 2], q[4 * i + 3]);
                dp[i] = make_float4(p[4 * i], p[4 * i + 1], p[4 * i + 2], p[4 * i + 3]);
            }
        }
    }
}

// w[b,t] = sum_m Phi_o[b,m] * y[b,m,t]  (fully parallel, memory/L3-bound)
__global__ void __launch_bounds__(256) w_kernel(
    const float* __restrict__ y,
    const float* __restrict__ Phi_o,
    float* __restrict__ w)
{
    const int b  = blockIdx.y;
    const int t4 = blockIdx.x * 256 + threadIdx.x;
    if (t4 >= NT / 4) return;

    const float4* yb = reinterpret_cast<const float4*>(y + (size_t)b * 2 * NM * NT);
    const float*  po = Phi_o + b * NM;

    float4 acc = make_float4(0.f, 0.f, 0.f, 0.f);
    #pragma unroll 8
    for (int mm = 0; mm < NM; ++mm) {
        float  c = po[mm];
        float4 v = yb[mm * (NT / 4) + t4];
        acc.x = fmaf(c, v.x, acc.x);
        acc.y = fmaf(c, v.y, acc.y);
        acc.z = fmaf(c, v.z, acc.z);
        acc.w = fmaf(c, v.w, acc.w);
    }
    reinterpret_cast<float4*>(w + (size_t)b * NT)[t4] = acc;
}

extern "C" void kernel_launch(void* const* d_in, const int* in_sizes, int n_in,
                              void* d_out, int out_size, void* d_ws, size_t ws_size,
                              hipStream_t stream)
{
    // inputs: 0=fs, 1=num_samples, 2=y0, 3=omega, 4=sigma, 5=gamma,
    //         6=Phi_e, 7=Phi_o, 8=fe_points
    const float* y0    = (const float*)d_in[2];
    const float* omega = (const float*)d_in[3];
    const float* sigma = (const float*)d_in[4];
    const float* gamma = (const float*)d_in[5];
    const float* Phi_e = (const float*)d_in[6];
    const float* Phi_o = (const float*)d_in[7];
    const float* fe    = (const float*)d_in[8];

    float* y_out = (float*)d_out;                    // (B, 2M, T)
    float* w_out = y_out + (size_t)NB * 2 * NM * NT; // (B, T)

    modal_scan_kernel<<<NB, 128, 0, stream>>>(y0, omega, sigma, gamma, Phi_e, fe, y_out);

    dim3 grid((NT / 4 + 255) / 256, NB);
    w_kernel<<<grid, 256, 0, stream>>>(y_out, Phi_o, w_out);
}